// Round 5
// baseline (112.676 us; speedup 1.0000x reference)
//
#include <hip/hip_runtime.h>

#define TL 2048
#define NHEAD 8
#define NLOC 4
#define L2E 1.44269504f

typedef __attribute__((ext_vector_type(4))) float f32x4;
typedef __attribute__((ext_vector_type(8))) __bf16 bf16x8;
typedef __attribute__((ext_vector_type(4))) __bf16 bf16x4;
typedef __attribute__((ext_vector_type(8))) unsigned short u16x8;

static __device__ __forceinline__ unsigned short f2bf(float f) {
    unsigned u = __float_as_uint(f);
    u = (u + 0x7FFFu + ((u >> 16) & 1u)) >> 16;
    return (unsigned short)u;
}
static __device__ __forceinline__ float bf2f(unsigned short u) {
    return __uint_as_float(((unsigned)u) << 16);
}
static __device__ __forceinline__ void gl_lds16(const void* g, void* l) {
    __builtin_amdgcn_global_load_lds(
        (const __attribute__((address_space(1))) void*)g,
        (__attribute__((address_space(3))) void*)l, 16, 0, 0);
}

// rel_scores[h', r] = dot(rel_pos_w[r, h'*64:+64], mlp_w[h']) * log2e -> f32
__global__ __launch_bounds__(256) void relscore_kernel(
    const float* __restrict__ rel_pos_w, const float* __restrict__ mlp_w,
    float* __restrict__ rel_sf) {
    int r = blockIdx.x;      // 0..4094
    int t = threadIdx.x;
    int w = t >> 6, lane = t & 63;
    float v = rel_pos_w[r * 256 + t] * mlp_w[t];
#pragma unroll
    for (int off = 32; off; off >>= 1) v += __shfl_xor(v, off);
    if (lane == 0) rel_sf[w * 4096 + r] = v * L2E;
}

// Per (bh, kt): K tile -> bf16 swizzled [64 k][8 chunks], V tile -> bf16
// transposed+swizzled [64 d][8 chunks]; chunk c of row r stored at c^(r&7).
// Fused: v_term[(b*4+h')*L + k] = dot(V[k,:], mlp_w[h']) * log2e (local h).
__global__ __launch_bounds__(256) void preconv_kernel(
    const float* __restrict__ key, const float* __restrict__ value,
    const float* __restrict__ mlp_w,
    unsigned short* __restrict__ Kb, unsigned short* __restrict__ Vtb,
    unsigned short* __restrict__ vtb) {
    __shared__ float Vf[64][66];
    int blk = blockIdx.x;            // bh*32 + kt
    int t = threadIdx.x;
    int bh = blk >> 5, kt = blk & 31;
    int h = bh & 7, b = bh >> 3;
    size_t src = (size_t)blk * 4096;
    size_t dst = (size_t)blk * 4096;

#pragma unroll
    for (int i = 0; i < 2; ++i) {
        int ch = t + i * 256;
        int row = ch >> 3, c = ch & 7;
        const float* kp = key + src + row * 64 + c * 8;
        f32x4 a = *(const f32x4*)kp;
        f32x4 bb = *(const f32x4*)(kp + 4);
        u16x8 o;
#pragma unroll
        for (int j = 0; j < 4; ++j) { o[j] = f2bf(a[j]); o[4 + j] = f2bf(bb[j]); }
        *(u16x8*)&Kb[dst + row * 64 + ((c ^ (row & 7)) << 3)] = o;
    }
    {
        int row = t >> 2, q4 = t & 3;
        const float* vp = value + src + row * 64 + q4 * 16;
#pragma unroll
        for (int j = 0; j < 4; ++j)
            *(f32x4*)&Vf[row][q4 * 16 + j * 4] = *(const f32x4*)(vp + j * 4);
    }
    __syncthreads();
#pragma unroll
    for (int i = 0; i < 2; ++i) {
        int ch = t + i * 256;
        int dr = ch >> 3, c = ch & 7;
        u16x8 o;
#pragma unroll
        for (int j = 0; j < 8; ++j) o[j] = f2bf(Vf[c * 8 + j][dr]);
        *(u16x8*)&Vtb[dst + dr * 64 + ((c ^ (dr & 7)) << 3)] = o;
    }
    if (h >= NLOC) {
        int wave = t >> 6, lane = t & 63;
        float mw = mlp_w[(h - NLOC) * 64 + lane];
        unsigned short* vout = vtb + (size_t)((b * NLOC + h - NLOC) * TL) + kt * 64;
#pragma unroll
        for (int i = 0; i < 16; ++i) {
            int row = wave * 16 + i;
            float v = Vf[row][lane] * mw;
#pragma unroll
            for (int off = 32; off; off >>= 1) v += __shfl_xor(v, off);
            if (lane == 0) vout[row] = f2bf(v * L2E);
        }
    }
}

// Flash attention, uniform-work blocks: 1 block = 1 bh x TWO complementary
// q-tiles (qbA = 31-pair, qbB = pair) as one 33-tile double-buffered stream.
// 4 waves x 16 q-rows. P overlaid into dead Ks[cur]; mid barrier lgkm-only.
__global__ __launch_bounds__(256, 2) void attn_kernel(
    const float* __restrict__ query,
    const unsigned short* __restrict__ Kb, const unsigned short* __restrict__ Vtb,
    const float* __restrict__ rel_sf, const unsigned short* __restrict__ vtb,
    float* __restrict__ out) {

    __shared__ __align__(16) unsigned char smem[59136];
    unsigned short* Ks0 = (unsigned short*)smem;            // [2][4096] u16
    unsigned short* Vt0 = (unsigned short*)(smem + 16384);  // [2][4096] u16
    float* relf  = (float*)(smem + 32768);                  // [2112] f32
    float* biasf = (float*)(smem + 41216);                  // [2][64] f32
    float* epil  = (float*)(smem + 41728);                  // [4][1088] f32

    int bid = blockIdx.x;          // 512 blocks
    int xslot = bid & 7, jj = bid >> 3;
    int pair = jj >> 2, sub = jj & 3;
    int bh = xslot * 4 + sub;      // all 16 pairs of a bh stay on one XCD
    int qbA = 31 - pair, qbB = pair;
    int h = bh & 7, b = bh >> 3;
    int t = threadIdx.x;
    int wave = t >> 6, lane = t & 63;
    int l15 = lane & 15, l4 = lane >> 4;
    bool islocal = (h >= NLOC);

    size_t base = (size_t)bh * TL * 64;
    const unsigned short* Ktiles = Kb + (size_t)bh * 32 * 4096;
    const unsigned short* Vtiles = Vtb + (size_t)bh * 32 * 4096;
    const unsigned short* vtp =
        vtb + (islocal ? (size_t)((b * NLOC + h - NLOC) * TL) : 0);

    // ---- prologue: async-stage tile 0 (pass A, kt=0); relf + biasf[0] ----
    gl_lds16(Ktiles + t * 8, Ks0 + t * 8);
    gl_lds16(Ktiles + 2048 + t * 8, Ks0 + 2048 + t * 8);
    gl_lds16(Vtiles + t * 8, Vt0 + t * 8);
    gl_lds16(Vtiles + 2048 + t * 8, Vt0 + 2048 + t * 8);
    if (islocal) {
        const f32x4* src = (const f32x4*)(rel_sf + (h - NLOC) * 4096);
        f32x4* dst = (f32x4*)relf;
        dst[t] = src[t];
        dst[t + 256] = src[t + 256];
        if (t < 16) dst[t + 512] = src[t + 512];
        if (t < 64) biasf[t] = bf2f(vtp[t]);
    }

    const float SC = 0.125f * L2E;
    auto loadQ = [&](int qrow, bf16x8& f0, bf16x8& f1) {
        const float* qsrc = query + base + (size_t)qrow * 64 + l4 * 8;
        f32x4 a = *(const f32x4*)qsrc;
        f32x4 bb = *(const f32x4*)(qsrc + 4);
        f32x4 c = *(const f32x4*)(qsrc + 32);
        f32x4 d = *(const f32x4*)(qsrc + 36);
        u16x8 u0, u1;
#pragma unroll
        for (int j = 0; j < 4; ++j) {
            u0[j] = f2bf(a[j] * SC); u0[4 + j] = f2bf(bb[j] * SC);
            u1[j] = f2bf(c[j] * SC); u1[4 + j] = f2bf(d[j] * SC);
        }
        f0 = __builtin_bit_cast(bf16x8, u0);
        f1 = __builtin_bit_cast(bf16x8, u1);
    };

    int qb = qbA;
    int qt = (qbA << 6) + wave * 16;
    int q = qt + l15;
    bf16x8 qf0, qf1;
    loadQ(q, qf0, qf1);

    float m = -1e30f, lsum = 0.0f;
    f32x4 acc0 = {0.f, 0.f, 0.f, 0.f};
    f32x4 acc1 = acc0, acc2 = acc0, acc3 = acc0;

    auto flush = [&]() {
        float invl = 1.0f / lsum;
        float* ob = epil + wave * 1088;   // per-wave [16][68] f32
        *(f32x4*)&ob[l15 * 68 + 0  + l4 * 4] = acc0 * invl;
        *(f32x4*)&ob[l15 * 68 + 16 + l4 * 4] = acc1 * invl;
        *(f32x4*)&ob[l15 * 68 + 32 + l4 * 4] = acc2 * invl;
        *(f32x4*)&ob[l15 * 68 + 48 + l4 * 4] = acc3 * invl;
        size_t obase = base + (size_t)qt * 64;
#pragma unroll
        for (int it = 0; it < 4; ++it) {
            int row = lane >> 2;
            int col = (lane & 3) * 16 + it * 4;
            f32x4 o = *(const f32x4*)&ob[row * 68 + col];
            *(f32x4*)(out + obase + (size_t)row * 64 + col) = o;
        }
    };

    __syncthreads();   // tile 0 + relf + biasf ready

    int cur = 0, ktbase = 0;
    for (int i = 0; i <= 32; ++i) {
        // ---- pass transition: flush A, reset state, switch to q-tile B ----
        if (i == qbA + 1) {
            flush();
            qb = qbB; ktbase = i;
            qt = (qbB << 6) + wave * 16;
            q = qt + l15;
            loadQ(q, qf0, qf1);
            m = -1e30f; lsum = 0.0f;
            acc0 = (f32x4){0.f, 0.f, 0.f, 0.f};
            acc1 = acc0; acc2 = acc0; acc3 = acc0;
        }
        int kt = i - ktbase;
        unsigned short* Ks = Ks0 + cur * 4096;
        unsigned short* Vt = Vt0 + cur * 4096;
        const float* bias = biasf + cur * 64;

        // ---- prefetch next stream tile (async) ----
        if (i < 32) {
            int nb = cur ^ 1;
            int nkt = (i + 1 <= qbA) ? (i + 1) : (i - qbA);
            const unsigned short* gk = Ktiles + (size_t)nkt * 4096;
            const unsigned short* gv = Vtiles + (size_t)nkt * 4096;
            gl_lds16(gk + t * 8, Ks0 + nb * 4096 + t * 8);
            gl_lds16(gk + 2048 + t * 8, Ks0 + nb * 4096 + 2048 + t * 8);
            gl_lds16(gv + t * 8, Vt0 + nb * 4096 + t * 8);
            gl_lds16(gv + 2048 + t * 8, Vt0 + nb * 4096 + 2048 + t * 8);
            if (islocal && t < 64) biasf[nb * 64 + t] = bf2f(vtp[nkt * 64 + t]);
        }

        int k0 = kt << 6;
        bool diag = (kt == qb);
        int s16max = diag ? wave : 3;   // wave-uniform; loops stay unrolled

        // ---- S^T = mfma(K, Q): lane holds q = qt+l15, k = k0+s16*16+l4*4+rg
        f32x4 sfr[4];
#pragma unroll
        for (int s16 = 0; s16 < 4; ++s16) {
            if (s16 <= s16max) {
                int r = s16 * 16 + l15;
                int sw = r & 7;
                const bf16x8 kf0 = *(const bf16x8*)&Ks[r * 64 + ((l4 ^ sw) << 3)];
                const bf16x8 kf1 = *(const bf16x8*)&Ks[r * 64 + (((4 + l4) ^ sw) << 3)];
                f32x4 z = {0.f, 0.f, 0.f, 0.f};
                z = __builtin_amdgcn_mfma_f32_16x16x32_bf16(kf0, qf0, z, 0, 0, 0);
                z = __builtin_amdgcn_mfma_f32_16x16x32_bf16(kf1, qf1, z, 0, 0, 0);
                sfr[s16] = z;
            } else {
                sfr[s16] = (f32x4){-1e30f, -1e30f, -1e30f, -1e30f};
            }
        }

        // ---- online softmax in exp2 domain ----
        float sv[16];
        float tmax = -1e30f;
#pragma unroll
        for (int s16 = 0; s16 < 4; ++s16) {
            f32x4 bv;
            if (islocal) bv = *(const f32x4*)&bias[s16 * 16 + l4 * 4];
#pragma unroll
            for (int rg = 0; rg < 4; ++rg) {
                int kk = s16 * 16 + l4 * 4 + rg;
                int k = k0 + kk;
                float s = sfr[s16][rg];
                if (s16 <= s16max) {
                    if (islocal) s += relf[k - q + 2047] + bv[rg];
                    if (diag && k > q) s = -1e30f;
                }
                sv[s16 * 4 + rg] = s;
                tmax = fmaxf(tmax, s);
            }
        }
        tmax = fmaxf(tmax, __shfl_xor(tmax, 16));
        tmax = fmaxf(tmax, __shfl_xor(tmax, 32));
        // defer-max (T13)
        if (__any(tmax > m + 11.5f)) {
            float newm = fmaxf(m, tmax);
            float corr = exp2f(m - newm);
            lsum *= corr;
            acc0 *= corr; acc1 *= corr; acc2 *= corr; acc3 *= corr;
            m = newm;
        }
        float psum = 0.f;
        bf16x4 pq[4];
#pragma unroll
        for (int s16 = 0; s16 < 4; ++s16) {
#pragma unroll
            for (int rg = 0; rg < 4; ++rg) {
                float p = exp2f(sv[s16 * 4 + rg] - m);
                psum += p;
                pq[s16][rg] = (__bf16)p;
            }
        }
        psum += __shfl_xor(psum, 16);
        psum += __shfl_xor(psum, 32);
        lsum += psum;

        // mid barrier: lgkm-only (do NOT drain in-flight gl_lds prefetch)
        asm volatile("s_waitcnt lgkmcnt(0)" ::: "memory");
        __builtin_amdgcn_s_barrier();
        __builtin_amdgcn_sched_barrier(0);

        // ---- P -> overlay into dead Ks[cur], wave-private [16 q][8 chunks] ----
        unsigned short* Pw = Ks + wave * 1024;
#pragma unroll
        for (int s16 = 0; s16 < 4; ++s16) {
            int c = 2 * s16 + (l4 >> 1);
            *(unsigned long long*)&Pw[l15 * 64 + ((c ^ (l15 & 7)) << 3) + ((l4 & 1) << 2)] =
                __builtin_bit_cast(unsigned long long, pq[s16]);
        }

        // ---- PV: O^T[d][q] += V^T[d][k] * P[q][k] ----
#pragma unroll
        for (int half = 0; half < 2; ++half) {
            const bf16x8 pf =
                *(const bf16x8*)&Pw[l15 * 64 + (((half * 4 + l4) ^ (l15 & 7)) << 3)];
            int cbase = half * 4 + l4;
#pragma unroll
            for (int dblk = 0; dblk < 4; ++dblk) {
                int r = dblk * 16 + l15;
                const bf16x8 vf =
                    *(const bf16x8*)&Vt[r * 64 + ((cbase ^ (r & 7)) << 3)];
                f32x4* ac = dblk == 0 ? &acc0 : dblk == 1 ? &acc1
                          : dblk == 2 ? &acc2 : &acc3;
                *ac = __builtin_amdgcn_mfma_f32_16x16x32_bf16(vf, pf, *ac, 0, 0, 0);
            }
        }

        __syncthreads();   // next tile staged (vmcnt+lgkm drain); PV done
        cur ^= 1;
    }

    flush();   // pass B output
}

extern "C" void kernel_launch(void* const* d_in, const int* in_sizes, int n_in,
                              void* d_out, int out_size, void* d_ws, size_t ws_size,
                              hipStream_t stream) {
    const float* query = (const float*)d_in[0];
    const float* key = (const float*)d_in[1];
    const float* value = (const float*)d_in[2];
    const float* rel_pos_w = (const float*)d_in[5];
    const float* mlp_w = (const float*)d_in[8];
    float* out = (float*)d_out;

    unsigned short* Kb = (unsigned short*)d_ws;        // 32*32*4096 u16 = 8 MiB
    unsigned short* Vtb = Kb + 32 * 32 * 4096;         // 8 MiB
    float* rel_sf = (float*)(Vtb + 32 * 32 * 4096);    // 4*4096 f32 = 64 KiB
    unsigned short* vtb = (unsigned short*)(rel_sf + 4 * 4096); // 32*2048 u16

    relscore_kernel<<<4095, 256, 0, stream>>>(rel_pos_w, mlp_w, rel_sf);
    preconv_kernel<<<1024, 256, 0, stream>>>(key, value, mlp_w, Kb, Vtb, vtb);
    attn_kernel<<<512, 256, 0, stream>>>(query, Kb, Vtb, rel_sf, vtb, out);
}

// Round 6
// 104.728 us; speedup vs baseline: 1.0759x; 1.0759x over previous
//
#include <hip/hip_runtime.h>

#define TL 2048
#define NHEAD 8
#define NLOC 4
#define L2E 1.44269504f
#define PART_STRIDE 4224   // f32 per partial: 4096 O^T + 64 m + 64 l

typedef __attribute__((ext_vector_type(4))) float f32x4;
typedef __attribute__((ext_vector_type(8))) __bf16 bf16x8;
typedef __attribute__((ext_vector_type(4))) __bf16 bf16x4;
typedef __attribute__((ext_vector_type(8))) unsigned short u16x8;

static __device__ __forceinline__ unsigned short f2bf(float f) {
    unsigned u = __float_as_uint(f);
    u = (u + 0x7FFFu + ((u >> 16) & 1u)) >> 16;
    return (unsigned short)u;
}
static __device__ __forceinline__ float bf2f(unsigned short u) {
    return __uint_as_float(((unsigned)u) << 16);
}
static __device__ __forceinline__ void gl_lds16(const void* g, void* l) {
    __builtin_amdgcn_global_load_lds(
        (const __attribute__((address_space(1))) void*)g,
        (__attribute__((address_space(3))) void*)l, 16, 0, 0);
}

// rel_scores[h', r] = dot(rel_pos_w[r, h'*64:+64], mlp_w[h']) * log2e -> bf16
__global__ __launch_bounds__(256) void relscore_kernel(
    const float* __restrict__ rel_pos_w, const float* __restrict__ mlp_w,
    unsigned short* __restrict__ rel_sb) {
    int r = blockIdx.x;      // 0..4094
    int t = threadIdx.x;
    int w = t >> 6, lane = t & 63;
    float v = rel_pos_w[r * 256 + t] * mlp_w[t];
#pragma unroll
    for (int off = 32; off; off >>= 1) v += __shfl_xor(v, off);
    if (lane == 0) rel_sb[w * 4096 + r] = f2bf(v * L2E);
}

// Per (bh, kt): K tile -> bf16 swizzled [64 k][8 chunks], V tile -> bf16
// transposed+swizzled [64 d][8 chunks]; chunk c of row r stored at c^(r&7).
// Fused: v_term[(b*4+h')*L + k] = dot(V[k,:], mlp_w[h']) * log2e (local h).
__global__ __launch_bounds__(256) void preconv_kernel(
    const float* __restrict__ key, const float* __restrict__ value,
    const float* __restrict__ mlp_w,
    unsigned short* __restrict__ Kb, unsigned short* __restrict__ Vtb,
    unsigned short* __restrict__ vtb) {
    __shared__ float Vf[64][66];
    int blk = blockIdx.x;            // bh*32 + kt
    int t = threadIdx.x;
    int bh = blk >> 5, kt = blk & 31;
    int h = bh & 7, b = bh >> 3;
    size_t src = (size_t)blk * 4096;
    size_t dst = (size_t)blk * 4096;

#pragma unroll
    for (int i = 0; i < 2; ++i) {
        int ch = t + i * 256;
        int row = ch >> 3, c = ch & 7;
        const float* kp = key + src + row * 64 + c * 8;
        f32x4 a = *(const f32x4*)kp;
        f32x4 bb = *(const f32x4*)(kp + 4);
        u16x8 o;
#pragma unroll
        for (int j = 0; j < 4; ++j) { o[j] = f2bf(a[j]); o[4 + j] = f2bf(bb[j]); }
        *(u16x8*)&Kb[dst + row * 64 + ((c ^ (row & 7)) << 3)] = o;
    }
    {
        int row = t >> 2, q4 = t & 3;
        const float* vp = value + src + row * 64 + q4 * 16;
#pragma unroll
        for (int j = 0; j < 4; ++j)
            *(f32x4*)&Vf[row][q4 * 16 + j * 4] = *(const f32x4*)(vp + j * 4);
    }
    __syncthreads();
#pragma unroll
    for (int i = 0; i < 2; ++i) {
        int ch = t + i * 256;
        int dr = ch >> 3, c = ch & 7;
        u16x8 o;
#pragma unroll
        for (int j = 0; j < 8; ++j) o[j] = f2bf(Vf[c * 8 + j][dr]);
        *(u16x8*)&Vtb[dst + dr * 64 + ((c ^ (dr & 7)) << 3)] = o;
    }
    if (h >= NLOC) {
        int wave = t >> 6, lane = t & 63;
        float mw = mlp_w[(h - NLOC) * 64 + lane];
        unsigned short* vout = vtb + (size_t)((b * NLOC + h - NLOC) * TL) + kt * 64;
#pragma unroll
        for (int i = 0; i < 16; ++i) {
            int row = wave * 16 + i;
            float v = Vf[row][lane] * mw;
#pragma unroll
            for (int off = 32; off; off >>= 1) v += __shfl_xor(v, off);
            if (lane == 0) vout[row] = f2bf(v * L2E);
        }
    }
}

// Flash attention. Work decomposition for load balance + backfill:
//   bid <  1024 : split blocks — (bh, qb>=16) halves A/B of the k-range,
//                 write unnormalized partials (O^T, m, l) to ws.
//   bid >= 1024 : single blocks — (bh, qb<=15), full k-range, write final.
// 1536 blocks > 4*256 resident slots -> scheduler backfills; heavy first.
__global__ __launch_bounds__(256, 4) void attn_kernel(
    const float* __restrict__ query,
    const unsigned short* __restrict__ Kb, const unsigned short* __restrict__ Vtb,
    const unsigned short* __restrict__ rel_sb, const unsigned short* __restrict__ vtb,
    float* __restrict__ out, float* __restrict__ part) {

    __shared__ __align__(16) unsigned char smem[37504];
    unsigned short* Ks0 = (unsigned short*)smem;            // [2][4096] u16
    unsigned short* Vt0 = (unsigned short*)(smem + 16384);  // [2][4096] u16
    unsigned short* relb = (unsigned short*)(smem + 32768); // [2112] bf16
    float* biasf = (float*)(smem + 36992);                  // [2][64] f32

    int bid = blockIdx.x;
    int bh, qb, ktb, kte;
    bool split;
    float* ppart = nullptr;
    if (bid < 1024) {
        int qbi = bid >> 6;          // 0..15 -> qb 31..16 (heavy first)
        qb = 31 - qbi;
        int half = bid & 1;
        bh = (bid >> 1) & 31;
        int sA = (qb + 1) >> 1;
        split = true;
        if (half == 0) { ktb = 0; kte = sA - 1; }
        else           { ktb = sA; kte = qb; }
        ppart = part + (size_t)(((qb - 16) * 32 + bh) * 2 + half) * PART_STRIDE;
    } else {
        int s = bid - 1024;
        qb = 15 - (s >> 5);
        bh = s & 31;
        ktb = 0; kte = qb;
        split = false;
    }

    int h = bh & 7, b = bh >> 3;
    int q0 = qb << 6;
    int t = threadIdx.x;
    int wave = t >> 6, lane = t & 63;
    int l15 = lane & 15, l4 = lane >> 4;
    bool islocal = (h >= NLOC);

    size_t base = (size_t)bh * TL * 64;
    const unsigned short* Ktiles = Kb + (size_t)bh * 32 * 4096;
    const unsigned short* Vtiles = Vtb + (size_t)bh * 32 * 4096;
    const unsigned short* vtp =
        vtb + (islocal ? (size_t)((b * NLOC + h - NLOC) * TL) : 0);

    // ---- prologue: async-stage tile ktb; copy relb + biasf[0] ----
    {
        const unsigned short* gk = Ktiles + (size_t)ktb * 4096;
        const unsigned short* gv = Vtiles + (size_t)ktb * 4096;
        gl_lds16(gk + t * 8, Ks0 + t * 8);
        gl_lds16(gk + 2048 + t * 8, Ks0 + 2048 + t * 8);
        gl_lds16(gv + t * 8, Vt0 + t * 8);
        gl_lds16(gv + 2048 + t * 8, Vt0 + 2048 + t * 8);
    }
    if (islocal) {
        const u16x8* src = (const u16x8*)(rel_sb + (h - NLOC) * 4096);
        u16x8* dst = (u16x8*)relb;
        dst[t] = src[t];
        if (t < 8) dst[256 + t] = src[256 + t];
        if (t < 64) biasf[t] = bf2f(vtp[ktb * 64 + t]);
    }

    int qt = q0 + wave * 16;
    int q = qt + l15;

    // Q fragments, pre-scaled by (1/sqrt(dk)) * log2e
    const float SC = 0.125f * L2E;
    bf16x8 qf0, qf1;
    {
        const float* qsrc = query + base + (size_t)q * 64 + l4 * 8;
        f32x4 a = *(const f32x4*)qsrc;
        f32x4 bb = *(const f32x4*)(qsrc + 4);
        f32x4 c = *(const f32x4*)(qsrc + 32);
        f32x4 d = *(const f32x4*)(qsrc + 36);
        u16x8 u0, u1;
#pragma unroll
        for (int j = 0; j < 4; ++j) {
            u0[j] = f2bf(a[j] * SC); u0[4 + j] = f2bf(bb[j] * SC);
            u1[j] = f2bf(c[j] * SC); u1[4 + j] = f2bf(d[j] * SC);
        }
        qf0 = __builtin_bit_cast(bf16x8, u0);
        qf1 = __builtin_bit_cast(bf16x8, u1);
    }

    float m = -1e30f, lsum = 0.0f;
    f32x4 acc0 = {0.f, 0.f, 0.f, 0.f};
    f32x4 acc1 = acc0, acc2 = acc0, acc3 = acc0;

    __syncthreads();   // tile ktb + relb + biasf ready

    int cur = 0;
    for (int kt = ktb; kt <= kte; ++kt) {
        unsigned short* Ks = Ks0 + cur * 4096;
        unsigned short* Vt = Vt0 + cur * 4096;
        const float* bias = biasf + cur * 64;

        // ---- prefetch tile kt+1 into the other buffer (async) ----
        if (kt < kte) {
            int nb = cur ^ 1;
            const unsigned short* gk = Ktiles + (size_t)(kt + 1) * 4096;
            const unsigned short* gv = Vtiles + (size_t)(kt + 1) * 4096;
            gl_lds16(gk + t * 8, Ks0 + nb * 4096 + t * 8);
            gl_lds16(gk + 2048 + t * 8, Ks0 + nb * 4096 + 2048 + t * 8);
            gl_lds16(gv + t * 8, Vt0 + nb * 4096 + t * 8);
            gl_lds16(gv + 2048 + t * 8, Vt0 + nb * 4096 + 2048 + t * 8);
            if (islocal && t < 64)
                biasf[nb * 64 + t] = bf2f(vtp[(kt + 1) * 64 + t]);
        }

        int k0 = kt << 6;
        bool diag = (kt == qb);
        int s16max = diag ? wave : 3;   // wave-uniform; loops stay unrolled

        // ---- S^T = mfma(K, Q): lane holds q = qt+l15, k = k0+s16*16+l4*4+rg
        f32x4 sfr[4];
#pragma unroll
        for (int s16 = 0; s16 < 4; ++s16) {
            if (s16 <= s16max) {
                int r = s16 * 16 + l15;
                int sw = r & 7;
                const bf16x8 kf0 = *(const bf16x8*)&Ks[r * 64 + ((l4 ^ sw) << 3)];
                const bf16x8 kf1 = *(const bf16x8*)&Ks[r * 64 + (((4 + l4) ^ sw) << 3)];
                f32x4 z = {0.f, 0.f, 0.f, 0.f};
                z = __builtin_amdgcn_mfma_f32_16x16x32_bf16(kf0, qf0, z, 0, 0, 0);
                z = __builtin_amdgcn_mfma_f32_16x16x32_bf16(kf1, qf1, z, 0, 0, 0);
                sfr[s16] = z;
            } else {
                sfr[s16] = (f32x4){-1e30f, -1e30f, -1e30f, -1e30f};
            }
        }

        // ---- online softmax in exp2 domain ----
        float sv[16];
        float tmax = -1e30f;
#pragma unroll
        for (int s16 = 0; s16 < 4; ++s16) {
            f32x4 bv;
            if (islocal) bv = *(const f32x4*)&bias[s16 * 16 + l4 * 4];
#pragma unroll
            for (int rg = 0; rg < 4; ++rg) {
                int kk = s16 * 16 + l4 * 4 + rg;
                int k = k0 + kk;
                float s = sfr[s16][rg];
                if (s16 <= s16max) {
                    if (islocal) s += bf2f(relb[k - q + 2047]) + bv[rg];
                    if (diag && k > q) s = -1e30f;
                }
                sv[s16 * 4 + rg] = s;
                tmax = fmaxf(tmax, s);
            }
        }
        tmax = fmaxf(tmax, __shfl_xor(tmax, 16));
        tmax = fmaxf(tmax, __shfl_xor(tmax, 32));
        // defer-max (T13)
        if (__any(tmax > m + 11.5f)) {
            float newm = fmaxf(m, tmax);
            float corr = exp2f(m - newm);
            lsum *= corr;
            acc0 *= corr; acc1 *= corr; acc2 *= corr; acc3 *= corr;
            m = newm;
        }
        float psum = 0.f;
        bf16x4 pq[4];
#pragma unroll
        for (int s16 = 0; s16 < 4; ++s16) {
#pragma unroll
            for (int rg = 0; rg < 4; ++rg) {
                float p = exp2f(sv[s16 * 4 + rg] - m);
                psum += p;
                pq[s16][rg] = (__bf16)p;
            }
        }
        psum += __shfl_xor(psum, 16);
        psum += __shfl_xor(psum, 32);
        lsum += psum;

        // mid barrier: lgkm-only (do NOT drain in-flight gl_lds prefetch)
        asm volatile("s_waitcnt lgkmcnt(0)" ::: "memory");
        __builtin_amdgcn_s_barrier();
        __builtin_amdgcn_sched_barrier(0);

        // ---- P -> overlay into dead Ks[cur], wave-private [16 q][8 chunks] ----
        unsigned short* Pw = Ks + wave * 1024;
#pragma unroll
        for (int s16 = 0; s16 < 4; ++s16) {
            int c = 2 * s16 + (l4 >> 1);
            *(unsigned long long*)&Pw[l15 * 64 + ((c ^ (l15 & 7)) << 3) + ((l4 & 1) << 2)] =
                __builtin_bit_cast(unsigned long long, pq[s16]);
        }

        // ---- PV: O^T[d][q] += V^T[d][k] * P[q][k] ----
#pragma unroll
        for (int half = 0; half < 2; ++half) {
            const bf16x8 pf =
                *(const bf16x8*)&Pw[l15 * 64 + (((half * 4 + l4) ^ (l15 & 7)) << 3)];
            int cbase = half * 4 + l4;
#pragma unroll
            for (int dblk = 0; dblk < 4; ++dblk) {
                int r = dblk * 16 + l15;
                const bf16x8 vf =
                    *(const bf16x8*)&Vt[r * 64 + ((cbase ^ (r & 7)) << 3)];
                f32x4* ac = dblk == 0 ? &acc0 : dblk == 1 ? &acc1
                          : dblk == 2 ? &acc2 : &acc3;
                *ac = __builtin_amdgcn_mfma_f32_16x16x32_bf16(vf, pf, *ac, 0, 0, 0);
            }
        }

        __syncthreads();   // next tile staged (vmcnt+lgkm drain); PV done
        cur ^= 1;
    }

    if (split) {
        // ---- unnormalized partial dump: O^T regs + m + l (coalesced) ----
        int slot = wave * 256 + l4 * 16 + l15;
        *(f32x4*)&ppart[(slot + 0)   * 4] = acc0;
        *(f32x4*)&ppart[(slot + 64)  * 4] = acc1;
        *(f32x4*)&ppart[(slot + 128) * 4] = acc2;
        *(f32x4*)&ppart[(slot + 192) * 4] = acc3;
        if (l4 == 0) {
            ppart[4096 + wave * 16 + l15] = m;
            ppart[4160 + wave * 16 + l15] = lsum;
        }
    } else {
        // ---- final: direct O^T stores (4 lanes cover contiguous 64B runs) ----
        float invl = 1.0f / lsum;
        float* ob = out + base + (size_t)q * 64 + l4 * 4;
        *(f32x4*)(ob + 0)  = acc0 * invl;
        *(f32x4*)(ob + 16) = acc1 * invl;
        *(f32x4*)(ob + 32) = acc2 * invl;
        *(f32x4*)(ob + 48) = acc3 * invl;
    }
}

// Combine the two k-range halves of each split q-tile.
__global__ __launch_bounds__(256) void merge_kernel(
    const float* __restrict__ part, float* __restrict__ out) {
    int bid = blockIdx.x;             // 512 = 16 qb x 32 bh
    int qb = 16 + (bid >> 5);
    int bh = bid & 31;
    const float* pA = part + (size_t)(((qb - 16) * 32 + bh) * 2) * PART_STRIDE;
    const float* pB = pA + PART_STRIDE;
    int t = threadIdx.x;
    int q = t >> 2, ds4 = t & 3;      // ds4*16 = d-segment base
    float ma = pA[4096 + q], la = pA[4160 + q];
    float mb = pB[4096 + q], lb = pB[4160 + q];
    float nm = fmaxf(ma, mb);
    float ca = exp2f(ma - nm), cb = exp2f(mb - nm);
    float inv = 1.0f / (la * ca + lb * cb);
    ca *= inv; cb *= inv;
    int s0 = ((q >> 4) * 256 + ds4 * 64 + (q & 15)) * 4;
    size_t obase = ((size_t)bh * TL + qb * 64 + q) * 64 + ds4 * 16;
#pragma unroll
    for (int j4 = 0; j4 < 4; ++j4) {
        f32x4 a = *(const f32x4*)&pA[s0 + j4 * 64];
        f32x4 b = *(const f32x4*)&pB[s0 + j4 * 64];
        f32x4 o = a * ca + b * cb;
        *(f32x4*)(out + obase + j4 * 4) = o;
    }
}

extern "C" void kernel_launch(void* const* d_in, const int* in_sizes, int n_in,
                              void* d_out, int out_size, void* d_ws, size_t ws_size,
                              hipStream_t stream) {
    const float* query = (const float*)d_in[0];
    const float* key = (const float*)d_in[1];
    const float* value = (const float*)d_in[2];
    const float* rel_pos_w = (const float*)d_in[5];
    const float* mlp_w = (const float*)d_in[8];
    float* out = (float*)d_out;

    unsigned short* Kb = (unsigned short*)d_ws;        // 8 MiB
    unsigned short* Vtb = Kb + 32 * 32 * 4096;         // 8 MiB
    unsigned short* rel_sb = Vtb + 32 * 32 * 4096;     // 32 KiB
    unsigned short* vtb = rel_sb + 4 * 4096;           // 128 KiB
    float* part = (float*)(vtb + 32 * 2048);           // 1024 * 4224 f32 = 16.5 MiB

    relscore_kernel<<<4095, 256, 0, stream>>>(rel_pos_w, mlp_w, rel_sb);
    preconv_kernel<<<1024, 256, 0, stream>>>(key, value, mlp_w, Kb, Vtb, vtb);
    attn_kernel<<<1536, 256, 0, stream>>>(query, Kb, Vtb, rel_sb, vtb, out, part);
    merge_kernel<<<512, 256, 0, stream>>>(part, out);
}